// Round 6
// baseline (150.815 us; speedup 1.0000x reference)
//
#include <hip/hip_runtime.h>

#define NROWS 8192
#define NCENT 4096
#define DIM   256

typedef short bf16x8 __attribute__((ext_vector_type(8)));
typedef float f32x4  __attribute__((ext_vector_type(4)));

// fp32 -> bf16 round-to-nearest-even
__device__ inline unsigned short f2bf(float f) {
    unsigned u = __float_as_uint(f);
    return (unsigned short)((u + 0x7fffu + ((u >> 16) & 1u)) >> 16);
}

// ---------------------------------------------------------------------------
// Prepass: fp32 -> bf16 convert (row-major) + row norms.
// ws layout: norms[12288] | xbf[8192*256] | cbf[4096*256]
// ---------------------------------------------------------------------------
__global__ __launch_bounds__(256) void prep_kernel(const float* __restrict__ x,
                                                   const float* __restrict__ c,
                                                   float* __restrict__ norms,
                                                   unsigned short* __restrict__ xbf,
                                                   unsigned short* __restrict__ cbf) {
    const int t = threadIdx.x, lane = t & 63;
    const int wbase = (blockIdx.x * 4 + (t >> 6)) * 4;
    #pragma unroll
    for (int rr = 0; rr < 4; ++rr) {
        const int gw = wbase + rr;                        // 0..12287
        const float* src;
        unsigned short* dst;
        if (gw < NROWS) { src = x + (size_t)gw * DIM;           dst = xbf + (size_t)gw * DIM; }
        else            { src = c + (size_t)(gw - NROWS) * DIM; dst = cbf + (size_t)(gw - NROWS) * DIM; }
        float4 v = ((const float4*)src)[lane];
        ushort4 b;
        b.x = f2bf(v.x); b.y = f2bf(v.y); b.z = f2bf(v.z); b.w = f2bf(v.w);
        ((ushort4*)dst)[lane] = b;
        float s = v.x * v.x + v.y * v.y + v.z * v.z + v.w * v.w;
        #pragma unroll
        for (int m = 32; m; m >>= 1) s += __shfl_xor(s, m);
        if (lane == 0) norms[gw] = s;
    }
}

// ---------------------------------------------------------------------------
// Main kernel (R6): NO LDS, NO barriers in the K-loop. Each wave loads its
// MFMA fragments global->VGPR directly (8 x 16B/lane per K-32 step) with a
// depth-1 software pipeline. Loads have register dests, so the compiler's
// own fine-grained s_waitcnt vmcnt(N) scheduling applies — this sidesteps
// the __syncthreads vmcnt(0) drain that capped R3/R4/R5 (the m97-structure
// plateau: barriers drain ALL in-flight global_load_lds every step).
// Fragment access pattern per load: 16 rows x 64B contiguous — L2-friendly;
// lines reused by partner waves (same block) and adjacent k-steps via L1.
// Block = 4 waves in 2x2 grid over a 128x128 tile; grid 2048 blocks with
// XCD-affinity remap (per-XCD stripe: A 512KB + B 2MB fits 4MB L2).
// ---------------------------------------------------------------------------
__global__ __launch_bounds__(256, 3) void rbf_mfma(const unsigned short* __restrict__ xbf,
                                                   const unsigned short* __restrict__ cbf,
                                                   const float* __restrict__ w,
                                                   const float* __restrict__ sigp,
                                                   const float* __restrict__ norms,
                                                   float* __restrict__ out) {
    const int t    = threadIdx.x;
    const int wave = t >> 6, lane = t & 63;

    // ---- XCD-affinity remap: each XCD gets an 8-m-tile x 32-n stripe ----
    const int lin = blockIdx.y * 32 + blockIdx.x;   // 0..2047, dispatch order
    const int xcd = lin & 7;
    const int pos = lin >> 3;                       // 0..255
    const int m0  = ((xcd << 3) + (pos >> 5)) * 128;
    const int n0  = (pos & 31) * 128;

    const int wy = wave >> 1, wx = wave & 1;
    const int lr = lane & 15;               // frag m/n index
    const int g  = lane >> 4;               // frag k-group / row-quad

    // ---- per-lane fragment base pointers (k-step advances via +s*32) ----
    const unsigned short* pa[4];
    const unsigned short* pb[4];
    #pragma unroll
    for (int i = 0; i < 4; ++i)
        pa[i] = xbf + (size_t)(m0 + 64 * wy + 16 * i + lr) * DIM + g * 8;
    #pragma unroll
    for (int j = 0; j < 4; ++j)
        pb[j] = cbf + (size_t)(n0 + 64 * wx + 16 * j + lr) * DIM + g * 8;

    f32x4 acc[4][4];
    #pragma unroll
    for (int i = 0; i < 4; ++i)
        #pragma unroll
        for (int j = 0; j < 4; ++j) acc[i][j] = f32x4{0, 0, 0, 0};

    bf16x8 a[4], b[4], an[4], bn[4];
    #pragma unroll
    for (int i = 0; i < 4; ++i) a[i] = *(const bf16x8*)(pa[i]);
    #pragma unroll
    for (int j = 0; j < 4; ++j) b[j] = *(const bf16x8*)(pb[j]);

    #pragma unroll
    for (int s = 0; s < 8; ++s) {
        if (s < 7) {   // prefetch step s+1 while MFMAs of step s run
            #pragma unroll
            for (int i = 0; i < 4; ++i) an[i] = *(const bf16x8*)(pa[i] + (s + 1) * 32);
            #pragma unroll
            for (int j = 0; j < 4; ++j) bn[j] = *(const bf16x8*)(pb[j] + (s + 1) * 32);
        }
        #pragma unroll
        for (int i = 0; i < 4; ++i)
            #pragma unroll
            for (int j = 0; j < 4; ++j)
                acc[i][j] = __builtin_amdgcn_mfma_f32_16x16x32_bf16(a[i], b[j], acc[i][j], 0, 0, 0);
        #pragma unroll
        for (int i = 0; i < 4; ++i) { a[i] = an[i]; b[i] = bn[i]; }
    }

    // ---- epilogue: phi = w*exp(-sigma*max(d2,0)); reduce 64 cols per row ----
    const float sigma = sigp[0];
    float c2v[4], wv[4];
    #pragma unroll
    for (int j = 0; j < 4; ++j) {
        int n = n0 + 64 * wx + 16 * j + lr;
        c2v[j] = norms[NROWS + n];
        wv[j]  = w[n];
    }

    #pragma unroll
    for (int i = 0; i < 4; ++i) {
        const int mbase = m0 + 64 * wy + 16 * i + 4 * g;   // 4 consecutive rows
        float4 x2v = *(const float4*)(norms + mbase);
        float rs[4] = {0.f, 0.f, 0.f, 0.f};
        #pragma unroll
        for (int j = 0; j < 4; ++j) {
            #pragma unroll
            for (int r = 0; r < 4; ++r) {
                float x2r = (r == 0) ? x2v.x : (r == 1) ? x2v.y : (r == 2) ? x2v.z : x2v.w;
                float d2 = x2r + c2v[j] - 2.0f * acc[i][j][r];
                d2 = fmaxf(d2, 0.0f);
                rs[r] += wv[j] * __expf(-sigma * d2);
            }
        }
        #pragma unroll
        for (int r = 0; r < 4; ++r) {
            rs[r] += __shfl_xor(rs[r], 1);
            rs[r] += __shfl_xor(rs[r], 2);
            rs[r] += __shfl_xor(rs[r], 4);
            rs[r] += __shfl_xor(rs[r], 8);
        }
        if (lr == 0) {
            #pragma unroll
            for (int r = 0; r < 4; ++r) atomicAdd(&out[mbase + r], rs[r]);
        }
    }
}

// ---------------------------------------------------------------------------
// Fallback (R2 kernels) if ws is too small for the bf16 scratch copies.
// ---------------------------------------------------------------------------
__global__ __launch_bounds__(256) void norms_kernel(const float* __restrict__ x,
                                                    const float* __restrict__ c,
                                                    float* __restrict__ ws) {
    int t = threadIdx.x, lane = t & 63;
    int gw = blockIdx.x * 4 + (t >> 6);
    const float* src;
    float* dst;
    if (gw < NROWS) { src = x + (size_t)gw * DIM;           dst = ws + gw; }
    else            { src = c + (size_t)(gw - NROWS) * DIM; dst = ws + gw; }
    float4 v = ((const float4*)src)[lane];
    float s = v.x * v.x + v.y * v.y + v.z * v.z + v.w * v.w;
    #pragma unroll
    for (int m = 32; m; m >>= 1) s += __shfl_xor(s, m);
    if (lane == 0) *dst = s;
}

__global__ __launch_bounds__(256) void rbf_kernel(const float* __restrict__ x,
                                                  const float* __restrict__ cent,
                                                  const float* __restrict__ w,
                                                  const float* __restrict__ sigp,
                                                  const float* __restrict__ norms,
                                                  float* __restrict__ out) {
    __shared__ __align__(16) short xs[64 * 32];
    __shared__ __align__(16) short cs[64 * 32];
    const int t = threadIdx.x;
    const int m0 = blockIdx.y * 64, n0 = blockIdx.x * 64;
    const int srow = t >> 2, seg = t & 3;
    const int pchunk = seg ^ ((srow >> 1) & 3);
    const int sidx = srow * 32 + pchunk * 8;
    const float* xg = x    + (size_t)(m0 + srow) * DIM + seg * 8;
    const float* cg = cent + (size_t)(n0 + srow) * DIM + seg * 8;
    const int lane = t & 63, wave = t >> 6;
    const int lr = lane & 15, lg = lane >> 4;
    const int arow = 16 * wave + lr;
    const int aidx = arow * 32 + ((lg ^ ((arow >> 1) & 3)) * 8);
    f32x4 acc[4] = {f32x4{0,0,0,0}, f32x4{0,0,0,0}, f32x4{0,0,0,0}, f32x4{0,0,0,0}};
    for (int k0 = 0; k0 < DIM; k0 += 32) {
        float4 f0 = *(const float4*)(xg + k0);
        float4 f1 = *(const float4*)(xg + k0 + 4);
        float4 g0 = *(const float4*)(cg + k0);
        float4 g1 = *(const float4*)(cg + k0 + 4);
        __syncthreads();
        union { unsigned short s[8]; int4 v; } ux, uc;
        ux.s[0]=f2bf(f0.x); ux.s[1]=f2bf(f0.y); ux.s[2]=f2bf(f0.z); ux.s[3]=f2bf(f0.w);
        ux.s[4]=f2bf(f1.x); ux.s[5]=f2bf(f1.y); ux.s[6]=f2bf(f1.z); ux.s[7]=f2bf(f1.w);
        uc.s[0]=f2bf(g0.x); uc.s[1]=f2bf(g0.y); uc.s[2]=f2bf(g0.z); uc.s[3]=f2bf(g0.w);
        uc.s[4]=f2bf(g1.x); uc.s[5]=f2bf(g1.y); uc.s[6]=f2bf(g1.z); uc.s[7]=f2bf(g1.w);
        *(int4*)(xs + sidx) = ux.v;
        *(int4*)(cs + sidx) = uc.v;
        __syncthreads();
        bf16x8 a = *(const bf16x8*)(xs + aidx);
        #pragma unroll
        for (int bt = 0; bt < 4; ++bt) {
            const int brow = 16 * bt + lr;
            bf16x8 b = *(const bf16x8*)(cs + brow * 32 + ((lg ^ ((brow >> 1) & 3)) * 8));
            acc[bt] = __builtin_amdgcn_mfma_f32_16x16x32_bf16(a, b, acc[bt], 0, 0, 0);
        }
    }
    const float sigma = sigp[0];
    const float* x2 = norms;
    const float* c2 = norms + NROWS;
    const int rbase = m0 + 16 * wave + lg * 4;
    float x2v[4];
    #pragma unroll
    for (int r = 0; r < 4; ++r) x2v[r] = x2[rbase + r];
    float rs[4] = {0.f, 0.f, 0.f, 0.f};
    #pragma unroll
    for (int bt = 0; bt < 4; ++bt) {
        const int col = n0 + 16 * bt + lr;
        const float c2v = c2[col];
        const float wvv = w[col];
        #pragma unroll
        for (int r = 0; r < 4; ++r) {
            float d2 = x2v[r] + c2v - 2.0f * acc[bt][r];
            d2 = fmaxf(d2, 0.0f);
            rs[r] += wvv * __expf(-sigma * d2);
        }
    }
    #pragma unroll
    for (int r = 0; r < 4; ++r) {
        rs[r] += __shfl_xor(rs[r], 1);
        rs[r] += __shfl_xor(rs[r], 2);
        rs[r] += __shfl_xor(rs[r], 4);
        rs[r] += __shfl_xor(rs[r], 8);
    }
    if (lr == 0) {
        #pragma unroll
        for (int r = 0; r < 4; ++r) atomicAdd(&out[rbase + r], rs[r]);
    }
}

extern "C" void kernel_launch(void* const* d_in, const int* in_sizes, int n_in,
                              void* d_out, int out_size, void* d_ws, size_t ws_size,
                              hipStream_t stream) {
    const float* x    = (const float*)d_in[0];
    const float* cent = (const float*)d_in[1];
    const float* w    = (const float*)d_in[2];
    const float* sig  = (const float*)d_in[3];
    float* out = (float*)d_out;

    const size_t norms_elems = NROWS + NCENT;              // 12288 floats
    const size_t xbf_off  = norms_elems * sizeof(float);
    const size_t cbf_off  = xbf_off + (size_t)NROWS * DIM * sizeof(unsigned short);
    const size_t ws_need  = cbf_off + (size_t)NCENT * DIM * sizeof(unsigned short);

    hipMemsetAsync(d_out, 0, (size_t)out_size * sizeof(float), stream);

    if (ws_size >= ws_need) {
        float* norms = (float*)d_ws;
        unsigned short* xbf = (unsigned short*)((char*)d_ws + xbf_off);
        unsigned short* cbf = (unsigned short*)((char*)d_ws + cbf_off);
        prep_kernel<<<(NROWS + NCENT) / 16, 256, 0, stream>>>(x, cent, norms, xbf, cbf);
        rbf_mfma<<<dim3(NCENT / 128, NROWS / 128), 256, 0, stream>>>(xbf, cbf, w, sig, norms, out);
    } else {
        float* norms = (float*)d_ws;
        norms_kernel<<<(NROWS + NCENT) / 4, 256, 0, stream>>>(x, cent, norms);
        rbf_kernel<<<dim3(NCENT / 64, NROWS / 64), 256, 0, stream>>>(x, cent, w, sig, norms, out);
    }
}

// Round 7
// 110.535 us; speedup vs baseline: 1.3644x; 1.3644x over previous
//
#include <hip/hip_runtime.h>

#define NROWS 8192
#define NCENT 4096
#define DIM   256

typedef short bf16x8 __attribute__((ext_vector_type(8)));
typedef float f32x4  __attribute__((ext_vector_type(4)));

// fp32 -> bf16 round-to-nearest-even
__device__ inline unsigned short f2bf(float f) {
    unsigned u = __float_as_uint(f);
    return (unsigned short)((u + 0x7fffu + ((u >> 16) & 1u)) >> 16);
}

// ---------------------------------------------------------------------------
// Norms: one wave per row. ws[0..8191]=||x||^2, ws[8192..12287]=||c||^2
// ---------------------------------------------------------------------------
__global__ __launch_bounds__(256) void norms_kernel(const float* __restrict__ x,
                                                    const float* __restrict__ c,
                                                    float* __restrict__ ws) {
    int t = threadIdx.x, lane = t & 63;
    int gw = blockIdx.x * 4 + (t >> 6);   // 0..12287
    const float* src;
    float* dst;
    if (gw < NROWS) { src = x + (size_t)gw * DIM;           dst = ws + gw; }
    else            { src = c + (size_t)(gw - NROWS) * DIM; dst = ws + gw; }
    float4 v = ((const float4*)src)[lane];
    float s = v.x * v.x + v.y * v.y + v.z * v.z + v.w * v.w;
    #pragma unroll
    for (int m = 32; m; m >>= 1) s += __shfl_xor(s, m);
    if (lane == 0) *dst = s;
}

// ---------------------------------------------------------------------------
// Pack: fp32 row-major -> bf16 MFMA-fragment-packed blocks.
// Block layout: for (rowgroup tg of 16 rows, kstep ks of 32 k), a contiguous
// 1KB block at (tg*8+ks)*1024B; within it, lane (g=lane>>4, lr=lane&15) owns
// bytes lane*16..+15 = rows tg*16+lr, k = ks*32+g*8..+7 (bf16x8) — exactly
// the 16x16x32 MFMA A/B fragment for that lane. One wave packs one block:
// its 1KB store is perfectly coalesced.
// ---------------------------------------------------------------------------
__global__ __launch_bounds__(256) void pack_kernel(const float* __restrict__ x,
                                                   const float* __restrict__ c,
                                                   unsigned short* __restrict__ xp,
                                                   unsigned short* __restrict__ cp) {
    const int t = threadIdx.x, lane = t & 63;
    const int task = blockIdx.x * 4 + (t >> 6);     // 0..6143
    const int lr = lane & 15, g = lane >> 4;
    const float* src;
    unsigned short* dst;
    int tg, ks;
    if (task < (NROWS / 16) * 8) {                  // x: 512 groups * 8 ksteps
        tg = task >> 3; ks = task & 7;
        src = x;  dst = xp + (size_t)task * 512;
    } else {
        int tk = task - (NROWS / 16) * 8;           // c: 256 groups * 8 ksteps
        tg = tk >> 3; ks = tk & 7;
        src = c;  dst = cp + (size_t)tk * 512;
    }
    const float* p = src + (size_t)(tg * 16 + lr) * DIM + ks * 32 + g * 8;
    float4 f0 = *(const float4*)p;
    float4 f1 = *(const float4*)(p + 4);
    union { unsigned short s[8]; int4 v; } u;
    u.s[0] = f2bf(f0.x); u.s[1] = f2bf(f0.y); u.s[2] = f2bf(f0.z); u.s[3] = f2bf(f0.w);
    u.s[4] = f2bf(f1.x); u.s[5] = f2bf(f1.y); u.s[6] = f2bf(f1.z); u.s[7] = f2bf(f1.w);
    *(int4*)(dst + lane * 8) = u.v;
}

// ---------------------------------------------------------------------------
// Main kernel (R7): ONE WAVE per block, 64x128 output tile (4 a-frags x
// 8 b-frags, 32 MFMA per K-32 step). No LDS, no barriers. Operands are
// pre-packed in fragment order, so every load is a fully-coalesced 1KB
// global_load_dwordx4 (16B/lane) — fixes R6's 16-line scatter. Depth-1
// register prefetch; compiler handles fine-grained vmcnt scheduling.
// XCD swizzle: each XCD gets a contiguous 16-m-tile x 32-n-tile stripe
// (A 512KB + B 2MB fits its 4MB L2).
// ---------------------------------------------------------------------------
__global__ __launch_bounds__(64, 2) void rbf_mfma(const unsigned short* __restrict__ xp,
                                                  const unsigned short* __restrict__ cp,
                                                  const float* __restrict__ w,
                                                  const float* __restrict__ sigp,
                                                  const float* __restrict__ norms,
                                                  float* __restrict__ out) {
    const int lane = threadIdx.x;           // 0..63 (one wave)
    const int lr = lane & 15, g = lane >> 4;

    // ---- XCD-affinity remap: 4096 blocks -> xcd stripe of 16m x 32n tiles ----
    const int lin = blockIdx.x;             // 0..4095, dispatch order
    const int xcd = lin & 7;
    const int pos = lin >> 3;               // 0..511
    const int mi  = xcd * 16 + (pos >> 5);  // 0..127 (64-row tiles)
    const int ni  = pos & 31;               // 0..31  (128-col tiles)
    const int m0  = mi * 64;
    const int n0  = ni * 128;

    // ---- packed fragment pointers: block (grp*8+ks)*512 shorts + lane*8 ----
    const unsigned short* pa[4];
    const unsigned short* pb[8];
    #pragma unroll
    for (int i = 0; i < 4; ++i)
        pa[i] = xp + ((size_t)((m0 >> 4) + i) * 8) * 512 + lane * 8;
    #pragma unroll
    for (int j = 0; j < 8; ++j)
        pb[j] = cp + ((size_t)((n0 >> 4) + j) * 8) * 512 + lane * 8;

    f32x4 acc[4][8];
    #pragma unroll
    for (int i = 0; i < 4; ++i)
        #pragma unroll
        for (int j = 0; j < 8; ++j) acc[i][j] = f32x4{0, 0, 0, 0};

    bf16x8 a[4], b[8], an[4], bn[8];
    #pragma unroll
    for (int i = 0; i < 4; ++i) a[i] = *(const bf16x8*)(pa[i]);
    #pragma unroll
    for (int j = 0; j < 8; ++j) b[j] = *(const bf16x8*)(pb[j]);

    #pragma unroll
    for (int s = 0; s < 8; ++s) {
        if (s < 7) {   // prefetch step s+1 (coalesced 1KB blocks) during MFMAs
            #pragma unroll
            for (int i = 0; i < 4; ++i) an[i] = *(const bf16x8*)(pa[i] + (s + 1) * 512);
            #pragma unroll
            for (int j = 0; j < 8; ++j) bn[j] = *(const bf16x8*)(pb[j] + (s + 1) * 512);
        }
        #pragma unroll
        for (int i = 0; i < 4; ++i)
            #pragma unroll
            for (int j = 0; j < 8; ++j)
                acc[i][j] = __builtin_amdgcn_mfma_f32_16x16x32_bf16(a[i], b[j], acc[i][j], 0, 0, 0);
        #pragma unroll
        for (int i = 0; i < 4; ++i) a[i] = an[i];
        #pragma unroll
        for (int j = 0; j < 8; ++j) b[j] = bn[j];
    }

    // ---- epilogue: phi = w*exp(-sigma*max(d2,0)); reduce 128 cols per row ----
    const float sigma = sigp[0];
    float c2v[8], wv[8];
    #pragma unroll
    for (int j = 0; j < 8; ++j) {
        int n = n0 + 16 * j + lr;
        c2v[j] = norms[NROWS + n];
        wv[j]  = w[n];
    }

    #pragma unroll
    for (int i = 0; i < 4; ++i) {
        const int mbase = m0 + 16 * i + 4 * g;     // 4 consecutive rows
        float4 x2v = *(const float4*)(norms + mbase);
        float rs[4] = {0.f, 0.f, 0.f, 0.f};
        #pragma unroll
        for (int j = 0; j < 8; ++j) {
            #pragma unroll
            for (int r = 0; r < 4; ++r) {
                float x2r = (r == 0) ? x2v.x : (r == 1) ? x2v.y : (r == 2) ? x2v.z : x2v.w;
                float d2 = x2r + c2v[j] - 2.0f * acc[i][j][r];
                d2 = fmaxf(d2, 0.0f);
                rs[r] += wv[j] * __expf(-sigma * d2);
            }
        }
        #pragma unroll
        for (int r = 0; r < 4; ++r) {
            rs[r] += __shfl_xor(rs[r], 1);
            rs[r] += __shfl_xor(rs[r], 2);
            rs[r] += __shfl_xor(rs[r], 4);
            rs[r] += __shfl_xor(rs[r], 8);
        }
        if (lr == 0) {
            #pragma unroll
            for (int r = 0; r < 4; ++r) atomicAdd(&out[mbase + r], rs[r]);
        }
    }
}

// ---------------------------------------------------------------------------
// Fallback (R2 kernel) if ws is too small for the packed scratch copies.
// ---------------------------------------------------------------------------
__global__ __launch_bounds__(256) void rbf_kernel(const float* __restrict__ x,
                                                  const float* __restrict__ cent,
                                                  const float* __restrict__ w,
                                                  const float* __restrict__ sigp,
                                                  const float* __restrict__ norms,
                                                  float* __restrict__ out) {
    __shared__ __align__(16) short xs[64 * 32];
    __shared__ __align__(16) short cs[64 * 32];
    const int t = threadIdx.x;
    const int m0 = blockIdx.y * 64, n0 = blockIdx.x * 64;
    const int srow = t >> 2, seg = t & 3;
    const int pchunk = seg ^ ((srow >> 1) & 3);
    const int sidx = srow * 32 + pchunk * 8;
    const float* xg = x    + (size_t)(m0 + srow) * DIM + seg * 8;
    const float* cg = cent + (size_t)(n0 + srow) * DIM + seg * 8;
    const int lane = t & 63, wave = t >> 6;
    const int lr = lane & 15, lg = lane >> 4;
    const int arow = 16 * wave + lr;
    const int aidx = arow * 32 + ((lg ^ ((arow >> 1) & 3)) * 8);
    f32x4 acc[4] = {f32x4{0,0,0,0}, f32x4{0,0,0,0}, f32x4{0,0,0,0}, f32x4{0,0,0,0}};
    for (int k0 = 0; k0 < DIM; k0 += 32) {
        float4 f0 = *(const float4*)(xg + k0);
        float4 f1 = *(const float4*)(xg + k0 + 4);
        float4 g0 = *(const float4*)(cg + k0);
        float4 g1 = *(const float4*)(cg + k0 + 4);
        __syncthreads();
        union { unsigned short s[8]; int4 v; } ux, uc;
        ux.s[0]=f2bf(f0.x); ux.s[1]=f2bf(f0.y); ux.s[2]=f2bf(f0.z); ux.s[3]=f2bf(f0.w);
        ux.s[4]=f2bf(f1.x); ux.s[5]=f2bf(f1.y); ux.s[6]=f2bf(f1.z); ux.s[7]=f2bf(f1.w);
        uc.s[0]=f2bf(g0.x); uc.s[1]=f2bf(g0.y); uc.s[2]=f2bf(g0.z); uc.s[3]=f2bf(g0.w);
        uc.s[4]=f2bf(g1.x); uc.s[5]=f2bf(g1.y); uc.s[6]=f2bf(g1.z); uc.s[7]=f2bf(g1.w);
        *(int4*)(xs + sidx) = ux.v;
        *(int4*)(cs + sidx) = uc.v;
        __syncthreads();
        bf16x8 a = *(const bf16x8*)(xs + aidx);
        #pragma unroll
        for (int bt = 0; bt < 4; ++bt) {
            const int brow = 16 * bt + lr;
            bf16x8 b = *(const bf16x8*)(cs + brow * 32 + ((lg ^ ((brow >> 1) & 3)) * 8));
            acc[bt] = __builtin_amdgcn_mfma_f32_16x16x32_bf16(a, b, acc[bt], 0, 0, 0);
        }
    }
    const float sigma = sigp[0];
    const int rbase = m0 + 16 * wave + lg * 4;
    float x2v[4];
    #pragma unroll
    for (int r = 0; r < 4; ++r) x2v[r] = norms[rbase + r];
    float rs[4] = {0.f, 0.f, 0.f, 0.f};
    #pragma unroll
    for (int bt = 0; bt < 4; ++bt) {
        const int col = n0 + 16 * bt + lr;
        const float c2v = norms[NROWS + col];
        const float wvv = w[col];
        #pragma unroll
        for (int r = 0; r < 4; ++r) {
            float d2 = x2v[r] + c2v - 2.0f * acc[bt][r];
            d2 = fmaxf(d2, 0.0f);
            rs[r] += wvv * __expf(-sigma * d2);
        }
    }
    #pragma unroll
    for (int r = 0; r < 4; ++r) {
        rs[r] += __shfl_xor(rs[r], 1);
        rs[r] += __shfl_xor(rs[r], 2);
        rs[r] += __shfl_xor(rs[r], 4);
        rs[r] += __shfl_xor(rs[r], 8);
    }
    if (lr == 0) {
        #pragma unroll
        for (int r = 0; r < 4; ++r) atomicAdd(&out[rbase + r], rs[r]);
    }
}

extern "C" void kernel_launch(void* const* d_in, const int* in_sizes, int n_in,
                              void* d_out, int out_size, void* d_ws, size_t ws_size,
                              hipStream_t stream) {
    const float* x    = (const float*)d_in[0];
    const float* cent = (const float*)d_in[1];
    const float* w    = (const float*)d_in[2];
    const float* sig  = (const float*)d_in[3];
    float* out = (float*)d_out;

    const size_t norms_elems = NROWS + NCENT;              // 12288 floats
    const size_t xp_off  = norms_elems * sizeof(float);
    const size_t cp_off  = xp_off + (size_t)NROWS * DIM * sizeof(unsigned short);
    const size_t ws_need = cp_off + (size_t)NCENT * DIM * sizeof(unsigned short);

    hipMemsetAsync(d_out, 0, (size_t)out_size * sizeof(float), stream);
    float* norms = (float*)d_ws;
    norms_kernel<<<(NROWS + NCENT) / 4, 256, 0, stream>>>(x, cent, norms);

    if (ws_size >= ws_need) {
        unsigned short* xp = (unsigned short*)((char*)d_ws + xp_off);
        unsigned short* cp = (unsigned short*)((char*)d_ws + cp_off);
        pack_kernel<<<((NROWS + NCENT) / 16 * 8) / 4, 256, 0, stream>>>(x, cent, xp, cp);
        rbf_mfma<<<(NROWS / 64) * (NCENT / 128), 64, 0, stream>>>(xp, cp, w, sig, norms, out);
    } else {
        rbf_kernel<<<dim3(NCENT / 64, NROWS / 64), 256, 0, stream>>>(x, cent, w, sig, norms, out);
    }
}